// Round 6
// baseline (300.340 us; speedup 1.0000x reference)
//
#include <hip/hip_runtime.h>
#include <math.h>

// Masked sparsemax, one wave per row, PERSISTENT grid-stride waves with
// register double-buffered row prefetch.
//
// R5 post-mortem: nt-loads got us 117->80 us (3.37 TB/s HBM), but the live
// ceiling on this machine is 6.7 TB/s (fillBuffer in the same rocprof pass).
// No pipe saturated (VALU 27%, occ 40%): the one-shot wave duty cycle is the
// cap -- each wave issues 16 loads, drains, then computes ~2000 cycles with
// ZERO memory ops in flight, then dies. Queues run dry periodically.
//
// Fix: each wave processes 4 rows (grid-stride). After converting row n's
// raw registers to z, it immediately issues row n+1's 16 nt-loads into the
// freed raw buffers; those loads fly UNDER row n's max/Michelot/store.
// Memory issue becomes continuous. Wave population unchanged (4096 waves =
// 1024 blocks, 4 blocks/CU, all resident; R3's overlap attempt failed by
// halving wave count -- this keeps it).
//
// Verified algorithm (R2/R5): Newton/Michelot on f(theta)=sum(max(z-theta,0)),
// theta0 = rowmax-1 (valid: p_max<=1), C via per-slot __ballot+__popcll
// (wave-uniform, scalar pipe), only f needs the 6-hop butterfly; nt-loads,
// regular stores (nt-stores measured harmful in R4).

constexpr int D    = 2048;
constexpr int TPB  = 256;            // 4 waves per block
constexpr int EPT  = D / 64;         // 32 elements per lane
constexpr int CHK  = EPT / 4;        // 8 float4 chunks per lane
constexpr int RPW  = 4;              // target rows per wave

typedef float f4 __attribute__((ext_vector_type(4)));
typedef int   i4 __attribute__((ext_vector_type(4)));

__global__ __launch_bounds__(TPB) void sparsemax_kernel(
    const float* __restrict__ x,
    const int*   __restrict__ mask,
    float*       __restrict__ out,
    int n_rows, int wstride)         // wstride = total wave count
{
    const int wave = threadIdx.x >> 6;
    const int lane = threadIdx.x & 63;
    int row = blockIdx.x * (TPB / 64) + wave;   // global wave id = first row
    if (row >= n_rows) return;                   // wave-uniform

    const int lo4 = lane * 4;

    // Raw double-buffer: next row's loads land here while current row (already
    // converted to z) is being processed.
    f4 xb[CHK]; i4 mb[CHK];
    {
        const size_t rb = (size_t)row * D;
        #pragma unroll
        for (int c = 0; c < CHK; ++c) {
            const size_t off = rb + (size_t)(c * 256 + lo4);
            xb[c] = __builtin_nontemporal_load((const f4*)(x    + off));
            mb[c] = __builtin_nontemporal_load((const i4*)(mask + off));
        }
    }

    for (;;) {
        const int nrow = row + wstride;

        // ---- consume raw buffers (compiler inserts the vmcnt wait here) ----
        float z[EPT];
        #pragma unroll
        for (int c = 0; c < CHK; ++c) {
            z[c * 4 + 0] = mb[c].x ? xb[c].x : -INFINITY;
            z[c * 4 + 1] = mb[c].y ? xb[c].y : -INFINITY;
            z[c * 4 + 2] = mb[c].z ? xb[c].z : -INFINITY;
            z[c * 4 + 3] = mb[c].w ? xb[c].w : -INFINITY;
        }

        // ---- issue next row's prefetch NOW; flies under the compute below ----
        if (nrow < n_rows) {
            const size_t rb = (size_t)nrow * D;
            #pragma unroll
            for (int c = 0; c < CHK; ++c) {
                const size_t off = rb + (size_t)(c * 256 + lo4);
                xb[c] = __builtin_nontemporal_load((const f4*)(x    + off));
                mb[c] = __builtin_nontemporal_load((const i4*)(mask + off));
            }
        }

        // ---- row max: 4 chains + butterfly ----
        float m0 = z[0], m1 = z[1], m2 = z[2], m3 = z[3];
        #pragma unroll
        for (int k = 4; k < EPT; k += 4) {
            m0 = fmaxf(m0, z[k + 0]);
            m1 = fmaxf(m1, z[k + 1]);
            m2 = fmaxf(m2, z[k + 2]);
            m3 = fmaxf(m3, z[k + 3]);
        }
        float gmax = fmaxf(fmaxf(m0, m1), fmaxf(m2, m3));
        #pragma unroll
        for (int off = 32; off > 0; off >>= 1)
            gmax = fmaxf(gmax, __shfl_xor(gmax, off, 64));

        // ---- Michelot/Newton ----
        float theta;
        if (gmax == -INFINITY) {
            theta = INFINITY;            // all-masked row -> all zeros
        } else {
            theta = gmax - 1.0f;
            int prevC = -1;
            for (int it = 0; it < 64; ++it) {
                float f0 = 0.0f, f1 = 0.0f, f2 = 0.0f, f3 = 0.0f;
                #pragma unroll
                for (int k = 0; k < EPT; k += 4) {
                    f0 += fmaxf(z[k + 0] - theta, 0.0f);
                    f1 += fmaxf(z[k + 1] - theta, 0.0f);
                    f2 += fmaxf(z[k + 2] - theta, 0.0f);
                    f3 += fmaxf(z[k + 3] - theta, 0.0f);
                }
                float f = (f0 + f1) + (f2 + f3);
                int C = 0;
                #pragma unroll
                for (int k = 0; k < EPT; ++k)
                    C += (int)__popcll(__ballot(z[k] > theta));
                #pragma unroll
                for (int off = 32; off > 0; off >>= 1)
                    f += __shfl_xor(f, off, 64);

                if (C == 0) break;
                if (C == prevC) break;   // set stable -> theta exact
                theta += (f - 1.0f) / (float)C;
                prevC = C;
            }
        }

        // ---- epilogue: p = max(z - theta, 0); regular cached stores ----
        {
            const size_t rb = (size_t)row * D;
            #pragma unroll
            for (int c = 0; c < CHK; ++c) {
                const size_t off = rb + (size_t)(c * 256 + lo4);
                float4 o;
                o.x = fmaxf(z[c * 4 + 0] - theta, 0.0f);
                o.y = fmaxf(z[c * 4 + 1] - theta, 0.0f);
                o.z = fmaxf(z[c * 4 + 2] - theta, 0.0f);
                o.w = fmaxf(z[c * 4 + 3] - theta, 0.0f);
                *(float4*)(out + off) = o;
            }
        }

        if (nrow >= n_rows) break;
        row = nrow;
    }
}

extern "C" void kernel_launch(void* const* d_in, const int* in_sizes, int n_in,
                              void* d_out, int out_size, void* d_ws, size_t ws_size,
                              hipStream_t stream) {
    const float* x    = (const float*)d_in[0];
    const int*   mask = (const int*)  d_in[1];
    float*       out  = (float*)d_out;
    const int n_rows = in_sizes[0] / D;
    // 4 rows per wave: all blocks co-resident (4 blocks/CU), no launch churn.
    int n_waves = (n_rows + RPW - 1) / RPW;
    int blocks  = (n_waves + (TPB / 64) - 1) / (TPB / 64);
    int wstride = blocks * (TPB / 64);
    sparsemax_kernel<<<blocks, TPB, 0, stream>>>(x, mask, out, n_rows, wstride);
}